// Round 1
// baseline (664.687 us; speedup 1.0000x reference)
//
#include <hip/hip_runtime.h>
#include <hip/hip_bf16.h>
#include <stdint.h>

#define B_   2
#define T_   2048
#define CEMB 2048
#define H_   16
#define HKV_ 4
#define D_   128

typedef __attribute__((ext_vector_type(8))) short bf16x8;   // 8 x bf16 (4 VGPR)
typedef __attribute__((ext_vector_type(4))) float f32x4;    // MFMA 16x16 accumulator

__device__ __forceinline__ unsigned short f2b(float f) {
  union { float f; unsigned u; } v; v.f = f;
  unsigned r = v.u + 0x7FFFu + ((v.u >> 16) & 1u);   // RNE
  return (unsigned short)(r >> 16);
}

// ---------------- f32 -> bf16 convert (vectorized) ----------------
__global__ void cvt_kernel(const float* __restrict__ src,
                           unsigned short* __restrict__ dst, int n4) {
  int i = blockIdx.x * blockDim.x + threadIdx.x;
  const int stride = gridDim.x * blockDim.x;
  for (; i < n4; i += stride) {
    float4 v = ((const float4*)src)[i];
    ushort4 o;
    o.x = f2b(v.x); o.y = f2b(v.y); o.z = f2b(v.z); o.w = f2b(v.w);
    ((ushort4*)dst)[i] = o;
  }
}

// ---------------- GEMM: C[M][N] = A[M][K] (bf16) * W[N][K]^T (bf16), f32 out --
#define BM 128
#define BN 128
#define BK 32

__global__ __launch_bounds__(256)
void gemm_bt(const unsigned short* __restrict__ A,
             const unsigned short* __restrict__ W,
             float* __restrict__ Cmat, int M, int N, int K) {
  __shared__ alignas(16) unsigned short As[BM * BK];
  __shared__ alignas(16) unsigned short Ws[BN * BK];

  const int tid  = threadIdx.x;
  const int lane = tid & 63;
  const int wv   = tid >> 6;
  const int wr   = wv >> 1, wc = wv & 1;      // 2x2 wave grid, 64x64 each
  const int l16  = lane & 15, g4 = lane >> 4; // MFMA lane decomposition
  const int m0 = blockIdx.y * BM;
  const int n0 = blockIdx.x * BN;

  // staging map: chunk (i*256+tid) -> row r = chunk>>2, 8-elem col group c4 = chunk&3
  const int r0 = tid >> 2;
  const int c4 = tid & 3;

  f32x4 acc[4][4] = {};

  const unsigned short* Aptr = A + (size_t)m0 * K;
  const unsigned short* Wptr = W + (size_t)n0 * K;

  const int nk = K / BK;
  bf16x8 pa[2], pw[2];
  // prologue prefetch of tile 0
  #pragma unroll
  for (int i = 0; i < 2; ++i) {
    pa[i] = *(const bf16x8*)(Aptr + (size_t)(r0 + i * 64) * K + c4 * 8);
    pw[i] = *(const bf16x8*)(Wptr + (size_t)(r0 + i * 64) * K + c4 * 8);
  }

  for (int kt = 0; kt < nk; ++kt) {
    __syncthreads();              // previous tile's compute done, LDS reusable
    #pragma unroll
    for (int i = 0; i < 2; ++i) { // XOR-swizzled ds_write_b128 (bank-spread)
      int r = r0 + i * 64;
      *(bf16x8*)&As[r * BK + ((c4 ^ (r & 3)) << 3)] = pa[i];
      *(bf16x8*)&Ws[r * BK + ((c4 ^ (r & 3)) << 3)] = pw[i];
    }
    __syncthreads();              // tile visible
    if (kt + 1 < nk) {            // prefetch next tile; latency hides under MFMA
      const int k0 = (kt + 1) * BK;
      #pragma unroll
      for (int i = 0; i < 2; ++i) {
        pa[i] = *(const bf16x8*)(Aptr + (size_t)(r0 + i * 64) * K + k0 + c4 * 8);
        pw[i] = *(const bf16x8*)(Wptr + (size_t)(r0 + i * 64) * K + k0 + c4 * 8);
      }
    }
    bf16x8 af[4], wf[4];
    #pragma unroll
    for (int mi = 0; mi < 4; ++mi) {
      int ar = wr * 64 + mi * 16 + l16;
      af[mi] = *(const bf16x8*)&As[ar * BK + ((g4 ^ (ar & 3)) << 3)];
    }
    #pragma unroll
    for (int ni = 0; ni < 4; ++ni) {
      int wrw = wc * 64 + ni * 16 + l16;
      wf[ni] = *(const bf16x8*)&Ws[wrw * BK + ((g4 ^ (wrw & 3)) << 3)];
    }
    #pragma unroll
    for (int mi = 0; mi < 4; ++mi) {
      #pragma unroll
      for (int ni = 0; ni < 4; ++ni) {
        acc[mi][ni] = __builtin_amdgcn_mfma_f32_16x16x32_bf16(
            af[mi], wf[ni], acc[mi][ni], 0, 0, 0);
      }
    }
  }

  // epilogue: C/D layout col = lane&15, row = (lane>>4)*4 + reg
  #pragma unroll
  for (int mi = 0; mi < 4; ++mi) {
    #pragma unroll
    for (int ni = 0; ni < 4; ++ni) {
      const int row = m0 + wr * 64 + mi * 16 + g4 * 4;
      const int col = n0 + wc * 64 + ni * 16 + l16;
      #pragma unroll
      for (int r = 0; r < 4; ++r)
        Cmat[(size_t)(row + r) * N + col] = acc[mi][ni][r];
    }
  }
}

// ---------------- fused RoPE + RMSNorm + scale + [B,H,T,D] bf16 write --------
__global__ __launch_bounds__(128)
void rope_norm(const float* __restrict__ X, const float* __restrict__ Cos,
               const float* __restrict__ Sin, unsigned short* __restrict__ Out,
               int Hn, float out_scale) {
  const int idx = blockIdx.x;        // over (b*T + t) * Hn + ... laid as bt*Hn + h
  const int h  = idx % Hn;
  const int bt = idx / Hn;
  const int t  = bt & (T_ - 1);
  const int b  = bt >> 11;           // T_ = 2048
  const int d  = threadIdx.x;        // 0..127
  const float* src = X + (size_t)bt * (Hn * D_) + h * D_;
  float y;
  if (d < 64) {
    float x1 = src[d], x2 = src[d + 64];
    float c = Cos[t * 64 + d], s = Sin[t * 64 + d];
    y = x1 * c + x2 * s;
  } else {
    int dd = d - 64;
    float x1 = src[dd], x2 = src[d];
    float c = Cos[t * 64 + dd], s = Sin[t * 64 + dd];
    y = -x1 * s + x2 * c;
  }
  float ss = y * y;
  #pragma unroll
  for (int m = 32; m; m >>= 1) ss += __shfl_xor(ss, m);
  __shared__ float red[2];
  if ((d & 63) == 0) red[d >> 6] = ss;
  __syncthreads();
  const float tot  = red[0] + red[1];
  const float rinv = rsqrtf(tot * (1.0f / 128.0f) + 1.1920929e-7f) * out_scale;
  Out[(((size_t)b * Hn + h) * T_ + t) * D_ + d] = f2b(y * rinv);
}

// ---------------- V: [B,T,HKV,D] f32 -> [B,HKV,D,T] bf16 (tiled transpose) ---
__global__ __launch_bounds__(256)
void vtrans(const float* __restrict__ Vf, unsigned short* __restrict__ Vt) {
  __shared__ float tile[32][65];
  const int t0 = blockIdx.x * 64;
  const int d0 = blockIdx.y * 32;
  const int bh = blockIdx.z;          // b*HKV + hk
  const int b = bh >> 2, hk = bh & 3;
  const int tid = threadIdx.x;
  {
    const int di = tid & 31, ts = tid >> 5;
    #pragma unroll
    for (int i = 0; i < 8; ++i) {
      int tt = ts + i * 8;
      tile[di][tt] = Vf[((size_t)(b * T_ + t0 + tt)) * (HKV_ * D_) + hk * D_ + d0 + di];
    }
  }
  __syncthreads();
  {
    const int ti = tid & 63, ds = tid >> 6;
    #pragma unroll
    for (int i = 0; i < 8; ++i) {
      int dd = ds * 8 + i;
      Vt[((size_t)bh * D_ + d0 + dd) * T_ + t0 + ti] = f2b(tile[dd][ti]);
    }
  }
}

// ---------------- flash attention, causal, 1 wave per 16-row Q tile ----------
// Qn: [B,H,T,D] bf16 (pre-scaled by 1/sqrt(D));  Kn: [B,HKV,T,D] bf16
// Vt: [B,HKV,D,T] bf16;  Yb out: [B*T][C] bf16
__global__ __launch_bounds__(64)
void attn_kernel(const unsigned short* __restrict__ Qn,
                 const unsigned short* __restrict__ Kn,
                 const unsigned short* __restrict__ Vt,
                 unsigned short* __restrict__ Yb) {
  __shared__ alignas(16) unsigned short plds[16 * 40];  // P[q][key] + pad
  const int lane = threadIdx.x;
  const int l16 = lane & 15, g4 = lane >> 4;
  const int qt = blockIdx.x;
  const int bh = blockIdx.y;
  const int b = bh >> 4, h = bh & 15;
  const int hk = h >> 2;                 // GQA: 4 q-heads per kv-head
  const int t0 = qt * 16;

  const unsigned short* qp = Qn + ((size_t)bh * T_ + t0) * D_;
  const unsigned short* kp = Kn + ((size_t)(b * HKV_ + hk) * T_) * D_;
  const unsigned short* vp = Vt + ((size_t)(b * HKV_ + hk) * D_) * T_;

  bf16x8 qf[4];
  #pragma unroll
  for (int kq = 0; kq < 4; ++kq)
    qf[kq] = *(const bf16x8*)(qp + (size_t)l16 * D_ + kq * 32 + g4 * 8);

  f32x4 o[8] = {};              // O^T acc: lane holds O^T[dt*16+g4*4+r][q=l16]
  float m_run = -3.0e38f, l_run = 0.f;

  const int ntiles = (t0 + 15) / 32 + 1;
  for (int kb = 0; kb < ntiles; ++kb) {
    const int kv0 = kb * 32;
    // S^T[key][q] = sum_d K[key][d] * Q[q][d]  (swapped operands)
    f32x4 sacc[2] = {};
    #pragma unroll
    for (int ss = 0; ss < 2; ++ss) {
      const unsigned short* kr = kp + (size_t)(kv0 + ss * 16 + l16) * D_;
      #pragma unroll
      for (int kq = 0; kq < 4; ++kq) {
        bf16x8 kf = *(const bf16x8*)(kr + kq * 32 + g4 * 8);
        sacc[ss] = __builtin_amdgcn_mfma_f32_16x16x32_bf16(kf, qf[kq], sacc[ss], 0, 0, 0);
      }
    }
    const int qglob = t0 + l16;
    float p[8];
    float pm = -3.0e38f;
    #pragma unroll
    for (int ss = 0; ss < 2; ++ss) {
      #pragma unroll
      for (int r = 0; r < 4; ++r) {
        int key = kv0 + ss * 16 + g4 * 4 + r;
        float sv = sacc[ss][r];
        sv = (key <= qglob) ? sv : -3.0e38f;   // causal mask (finite sentinel)
        p[ss * 4 + r] = sv;
        pm = fmaxf(pm, sv);
      }
    }
    pm = fmaxf(pm, __shfl_xor(pm, 16));
    pm = fmaxf(pm, __shfl_xor(pm, 32));
    const float m_new = fmaxf(m_run, pm);
    const float alpha = __expf(m_run - m_new);
    float lsum = 0.f;
    #pragma unroll
    for (int i = 0; i < 8; ++i) { float e = __expf(p[i] - m_new); p[i] = e; lsum += e; }
    lsum += __shfl_xor(lsum, 16);
    lsum += __shfl_xor(lsum, 32);
    l_run = l_run * alpha + lsum;
    m_run = m_new;
    #pragma unroll
    for (int i = 0; i < 8; ++i) o[i] *= alpha;

    // P[q][key] -> LDS (row stride 40 elems; b64 writes, b128 read below)
    #pragma unroll
    for (int ss = 0; ss < 2; ++ss) {
      unsigned w0 = ((unsigned)f2b(p[ss * 4 + 1]) << 16) | f2b(p[ss * 4 + 0]);
      unsigned w1 = ((unsigned)f2b(p[ss * 4 + 3]) << 16) | f2b(p[ss * 4 + 2]);
      uint2 u; u.x = w0; u.y = w1;
      *(uint2*)&plds[l16 * 40 + ss * 16 + g4 * 4] = u;
    }
    // B-operand: lane holds P[col=l16][k=g4*8+j]  (LDS in-order within wave)
    bf16x8 pf = *(const bf16x8*)&plds[l16 * 40 + g4 * 8];

    // O^T[d][q] += sum_key V^T[d][key] * P[q][key]
    #pragma unroll
    for (int dt = 0; dt < 8; ++dt) {
      bf16x8 vf = *(const bf16x8*)(vp + (size_t)(dt * 16 + l16) * T_ + kv0 + g4 * 8);
      o[dt] = __builtin_amdgcn_mfma_f32_16x16x32_bf16(vf, pf, o[dt], 0, 0, 0);
    }
  }

  const float inv_l = 1.0f / l_run;
  unsigned short* yrow = Yb + ((size_t)(b * T_ + t0 + l16) * CEMB) + h * D_;
  #pragma unroll
  for (int dt = 0; dt < 8; ++dt) {
    #pragma unroll
    for (int r = 0; r < 4; ++r)
      yrow[dt * 16 + g4 * 4 + r] = f2b(o[dt][r] * inv_l);
  }
}

// ---------------------------------------------------------------------------
extern "C" void kernel_launch(void* const* d_in, const int* in_sizes, int n_in,
                              void* d_out, int out_size, void* d_ws, size_t ws_size,
                              hipStream_t stream) {
  const float* x    = (const float*)d_in[0];
  const float* cosp = (const float*)d_in[1];
  const float* sinp = (const float*)d_in[2];
  const float* Wq   = (const float*)d_in[3];
  const float* Wk   = (const float*)d_in[4];
  const float* Wv   = (const float*)d_in[5];
  const float* Wo   = (const float*)d_in[6];
  float* out = (float*)d_out;

  char* ws = (char*)d_ws;
  size_t off = 0;
  auto alloc = [&](size_t bytes) {
    void* p = ws + off;
    off += (bytes + 255) & ~(size_t)255;
    return p;
  };
  const size_t MT = (size_t)B_ * T_;  // 4096
  unsigned short* xb  = (unsigned short*)alloc(MT * CEMB * 2);
  unsigned short* wqb = (unsigned short*)alloc((size_t)2048 * 2048 * 2);
  unsigned short* wkb = (unsigned short*)alloc((size_t)512 * 2048 * 2);
  unsigned short* wvb = (unsigned short*)alloc((size_t)512 * 2048 * 2);
  unsigned short* wob = (unsigned short*)alloc((size_t)2048 * 2048 * 2);
  float* qf = (float*)alloc(MT * 2048 * 4);
  float* kf = (float*)alloc(MT * 512 * 4);
  float* vf = (float*)alloc(MT * 512 * 4);
  unsigned short* qn = (unsigned short*)alloc((size_t)B_ * H_ * T_ * D_ * 2);
  unsigned short* kn = (unsigned short*)alloc((size_t)B_ * HKV_ * T_ * D_ * 2);
  unsigned short* vt = (unsigned short*)alloc((size_t)B_ * HKV_ * D_ * T_ * 2);
  unsigned short* yb = (unsigned short*)alloc(MT * CEMB * 2);

  // bf16 casts
  cvt_kernel<<<2048, 256, 0, stream>>>(x,  xb,  (int)(MT * CEMB / 4));
  cvt_kernel<<<1024, 256, 0, stream>>>(Wq, wqb, 2048 * 2048 / 4);
  cvt_kernel<<<256,  256, 0, stream>>>(Wk, wkb, 512 * 2048 / 4);
  cvt_kernel<<<256,  256, 0, stream>>>(Wv, wvb, 512 * 2048 / 4);
  cvt_kernel<<<1024, 256, 0, stream>>>(Wo, wob, 2048 * 2048 / 4);

  // projections (C = x @ W^T)
  gemm_bt<<<dim3(2048 / BN, 4096 / BM), 256, 0, stream>>>(xb, wqb, qf, 4096, 2048, 2048);
  gemm_bt<<<dim3(512 / BN,  4096 / BM), 256, 0, stream>>>(xb, wkb, kf, 4096, 512, 2048);
  gemm_bt<<<dim3(512 / BN,  4096 / BM), 256, 0, stream>>>(xb, wvb, vf, 4096, 512, 2048);

  // RoPE + RMSNorm (+ fold 1/sqrt(D) into Q), layout to [B,H,T,D]
  rope_norm<<<4096 * H_,  128, 0, stream>>>(qf, cosp, sinp, qn, H_,  0.08838834764831845f);
  rope_norm<<<4096 * HKV_, 128, 0, stream>>>(kf, cosp, sinp, kn, HKV_, 1.0f);
  vtrans<<<dim3(T_ / 64, D_ / 32, B_ * HKV_), 256, 0, stream>>>(vf, vt);

  // causal flash attention
  attn_kernel<<<dim3(T_ / 16, B_ * H_), 64, 0, stream>>>(qn, kn, vt, yb);

  // output projection -> f32 d_out
  gemm_bt<<<dim3(2048 / BN, 4096 / BM), 256, 0, stream>>>(yb, wob, out, 4096, 2048, 2048);
}

// Round 2
// 445.758 us; speedup vs baseline: 1.4911x; 1.4911x over previous
//
#include <hip/hip_runtime.h>
#include <hip/hip_bf16.h>
#include <stdint.h>

#define B_   2
#define T_   2048
#define CEMB 2048
#define H_   16
#define HKV_ 4
#define D_   128

typedef __attribute__((ext_vector_type(8))) short bf16x8;   // 8 x bf16 (4 VGPR)
typedef __attribute__((ext_vector_type(4))) float f32x4;    // MFMA 16x16 accumulator

#if __has_builtin(__builtin_amdgcn_exp2f)
#define EXP2(x) __builtin_amdgcn_exp2f(x)
#else
#define EXP2(x) exp2f(x)
#endif

__device__ __forceinline__ unsigned short f2b(float f) {
  union { float f; unsigned u; } v; v.f = f;
  unsigned r = v.u + 0x7FFFu + ((v.u >> 16) & 1u);   // RNE
  return (unsigned short)(r >> 16);
}

// ---------------- f32 -> bf16 convert (vectorized) ----------------
__global__ void cvt_kernel(const float* __restrict__ src,
                           unsigned short* __restrict__ dst, int n4) {
  int i = blockIdx.x * blockDim.x + threadIdx.x;
  const int stride = gridDim.x * blockDim.x;
  for (; i < n4; i += stride) {
    float4 v = ((const float4*)src)[i];
    ushort4 o;
    o.x = f2b(v.x); o.y = f2b(v.y); o.z = f2b(v.z); o.w = f2b(v.w);
    ((ushort4*)dst)[i] = o;
  }
}

// ---------------- GEMM: C[M][N] = A[M][K] (bf16) * W[N][K]^T (bf16), f32 out --
#define BM 128
#define BN 128
#define BK 32

__global__ __launch_bounds__(256)
void gemm_bt(const unsigned short* __restrict__ A,
             const unsigned short* __restrict__ W,
             float* __restrict__ Cmat, int M, int N, int K) {
  __shared__ alignas(16) unsigned short As[BM * BK];
  __shared__ alignas(16) unsigned short Ws[BN * BK];

  const int tid  = threadIdx.x;
  const int lane = tid & 63;
  const int wv   = tid >> 6;
  const int wr   = wv >> 1, wc = wv & 1;      // 2x2 wave grid, 64x64 each
  const int l16  = lane & 15, g4 = lane >> 4; // MFMA lane decomposition
  const int m0 = blockIdx.y * BM;
  const int n0 = blockIdx.x * BN;

  const int r0 = tid >> 2;
  const int c4 = tid & 3;

  f32x4 acc[4][4] = {};

  const unsigned short* Aptr = A + (size_t)m0 * K;
  const unsigned short* Wptr = W + (size_t)n0 * K;

  const int nk = K / BK;
  bf16x8 pa[2], pw[2];
  #pragma unroll
  for (int i = 0; i < 2; ++i) {
    pa[i] = *(const bf16x8*)(Aptr + (size_t)(r0 + i * 64) * K + c4 * 8);
    pw[i] = *(const bf16x8*)(Wptr + (size_t)(r0 + i * 64) * K + c4 * 8);
  }

  for (int kt = 0; kt < nk; ++kt) {
    __syncthreads();
    #pragma unroll
    for (int i = 0; i < 2; ++i) {
      int r = r0 + i * 64;
      *(bf16x8*)&As[r * BK + ((c4 ^ (r & 3)) << 3)] = pa[i];
      *(bf16x8*)&Ws[r * BK + ((c4 ^ (r & 3)) << 3)] = pw[i];
    }
    __syncthreads();
    if (kt + 1 < nk) {
      const int k0 = (kt + 1) * BK;
      #pragma unroll
      for (int i = 0; i < 2; ++i) {
        pa[i] = *(const bf16x8*)(Aptr + (size_t)(r0 + i * 64) * K + k0 + c4 * 8);
        pw[i] = *(const bf16x8*)(Wptr + (size_t)(r0 + i * 64) * K + k0 + c4 * 8);
      }
    }
    bf16x8 af[4], wf[4];
    #pragma unroll
    for (int mi = 0; mi < 4; ++mi) {
      int ar = wr * 64 + mi * 16 + l16;
      af[mi] = *(const bf16x8*)&As[ar * BK + ((g4 ^ (ar & 3)) << 3)];
    }
    #pragma unroll
    for (int ni = 0; ni < 4; ++ni) {
      int wrw = wc * 64 + ni * 16 + l16;
      wf[ni] = *(const bf16x8*)&Ws[wrw * BK + ((g4 ^ (wrw & 3)) << 3)];
    }
    #pragma unroll
    for (int mi = 0; mi < 4; ++mi) {
      #pragma unroll
      for (int ni = 0; ni < 4; ++ni) {
        acc[mi][ni] = __builtin_amdgcn_mfma_f32_16x16x32_bf16(
            af[mi], wf[ni], acc[mi][ni], 0, 0, 0);
      }
    }
  }

  #pragma unroll
  for (int mi = 0; mi < 4; ++mi) {
    #pragma unroll
    for (int ni = 0; ni < 4; ++ni) {
      const int row = m0 + wr * 64 + mi * 16 + g4 * 4;
      const int col = n0 + wc * 64 + ni * 16 + l16;
      #pragma unroll
      for (int r = 0; r < 4; ++r)
        Cmat[(size_t)(row + r) * N + col] = acc[mi][ni][r];
    }
  }
}

// ---------------- fused RoPE + RMSNorm + scale + [B,H,T,D] bf16 write --------
__global__ __launch_bounds__(128)
void rope_norm(const float* __restrict__ X, const float* __restrict__ Cos,
               const float* __restrict__ Sin, unsigned short* __restrict__ Out,
               int Hn, float out_scale) {
  const int idx = blockIdx.x;
  const int h  = idx % Hn;
  const int bt = idx / Hn;
  const int t  = bt & (T_ - 1);
  const int b  = bt >> 11;
  const int d  = threadIdx.x;        // 0..127
  const float* src = X + (size_t)bt * (Hn * D_) + h * D_;
  float y;
  if (d < 64) {
    float x1 = src[d], x2 = src[d + 64];
    float c = Cos[t * 64 + d], s = Sin[t * 64 + d];
    y = x1 * c + x2 * s;
  } else {
    int dd = d - 64;
    float x1 = src[dd], x2 = src[d];
    float c = Cos[t * 64 + dd], s = Sin[t * 64 + dd];
    y = -x1 * s + x2 * c;
  }
  float ss = y * y;
  #pragma unroll
  for (int m = 32; m; m >>= 1) ss += __shfl_xor(ss, m);
  __shared__ float red[2];
  if ((d & 63) == 0) red[d >> 6] = ss;
  __syncthreads();
  const float tot  = red[0] + red[1];
  const float rinv = rsqrtf(tot * (1.0f / 128.0f) + 1.1920929e-7f) * out_scale;
  Out[(((size_t)b * Hn + h) * T_ + t) * D_ + d] = f2b(y * rinv);
}

// ---------------- V: [B,T,HKV,D] f32 -> [B,HKV,D,T] bf16 (tiled transpose) ---
__global__ __launch_bounds__(256)
void vtrans(const float* __restrict__ Vf, unsigned short* __restrict__ Vt) {
  __shared__ float tile[32][65];
  const int t0 = blockIdx.x * 64;
  const int d0 = blockIdx.y * 32;
  const int bh = blockIdx.z;
  const int b = bh >> 2, hk = bh & 3;
  const int tid = threadIdx.x;
  {
    const int di = tid & 31, ts = tid >> 5;
    #pragma unroll
    for (int i = 0; i < 8; ++i) {
      int tt = ts + i * 8;
      tile[di][tt] = Vf[((size_t)(b * T_ + t0 + tt)) * (HKV_ * D_) + hk * D_ + d0 + di];
    }
  }
  __syncthreads();
  {
    const int ti = tid & 63, ds = tid >> 6;
    #pragma unroll
    for (int i = 0; i < 8; ++i) {
      int dd = ds * 8 + i;
      Vt[((size_t)bh * D_ + d0 + dd) * T_ + t0 + ti] = f2b(tile[dd][ti]);
    }
  }
}

// ---------------- flash attention, causal ------------------------------------
// 1 wave per block; QBLK=32 rows/wave (2 frags), KVBLK=64 keys/iter (4 frags).
// Qn: [B,H,T,D] bf16, pre-scaled by (1/sqrt(D))*log2(e) -> softmax in exp2 domain
// Kn: [B,HKV,T,D] bf16;  Vt: [B,HKV,D,T] bf16;  Yb out: [B*T][C] bf16
#define PST 72   // plds row stride (elems): 144 B = 16B-aligned, conflict-min b128 reads

__global__ __launch_bounds__(64, 2)
void attn_kernel(const unsigned short* __restrict__ Qn,
                 const unsigned short* __restrict__ Kn,
                 const unsigned short* __restrict__ Vt,
                 unsigned short* __restrict__ Yb) {
  __shared__ alignas(16) unsigned short plds[2 * 16 * PST];
  const int lane = threadIdx.x;
  const int l16 = lane & 15, g4 = lane >> 4;
  const int qt = blockIdx.x;
  const int bh = blockIdx.y;
  const int b = bh >> 4, h = bh & 15;
  const int hk = h >> 2;                 // GQA: 4 q-heads per kv-head
  const int t0 = qt * 32;

  const unsigned short* qp = Qn + ((size_t)bh * T_ + t0) * D_;
  const unsigned short* kp = Kn + ((size_t)(b * HKV_ + hk) * T_) * D_;
  const unsigned short* vp = Vt + ((size_t)(b * HKV_ + hk) * D_) * T_;

  bf16x8 qf[2][4];
  #pragma unroll
  for (int qi = 0; qi < 2; ++qi)
    #pragma unroll
    for (int kq = 0; kq < 4; ++kq)
      qf[qi][kq] = *(const bf16x8*)(qp + (size_t)(qi * 16 + l16) * D_ + kq * 32 + g4 * 8);

  f32x4 o[2][8] = {};           // O^T acc: lane holds O^T[dt*16+g4*4+r][q=l16]
  float m_run[2] = {-3.0e38f, -3.0e38f};
  float l_run[2] = {0.f, 0.f};

  const int niter = t0 / 64 + 1;
  for (int kb = 0; kb < niter; ++kb) {
    const int kv0 = kb * 64;
    // S^T[key][q] = sum_d K[key][d] * Q[q][d]  (swapped operands)
    f32x4 sacc[2][4] = {};
    #pragma unroll
    for (int ss = 0; ss < 4; ++ss) {
      const unsigned short* kr = kp + (size_t)(kv0 + ss * 16 + l16) * D_;
      bf16x8 kf[4];
      #pragma unroll
      for (int kq = 0; kq < 4; ++kq) kf[kq] = *(const bf16x8*)(kr + kq * 32 + g4 * 8);
      #pragma unroll
      for (int qi = 0; qi < 2; ++qi)
        #pragma unroll
        for (int kq = 0; kq < 4; ++kq)
          sacc[qi][ss] = __builtin_amdgcn_mfma_f32_16x16x32_bf16(kf[kq], qf[qi][kq], sacc[qi][ss], 0, 0, 0);
    }
    const bool need_mask = (kv0 + 63 > t0);   // else every key <= t0 <= all qglob
    #pragma unroll
    for (int qi = 0; qi < 2; ++qi) {
      const int qglob = t0 + qi * 16 + l16;
      float p[16];
      float pm = -3.0e38f;
      #pragma unroll
      for (int ss = 0; ss < 4; ++ss) {
        #pragma unroll
        for (int r = 0; r < 4; ++r) {
          float sv = sacc[qi][ss][r];
          if (need_mask) {
            int key = kv0 + ss * 16 + g4 * 4 + r;
            sv = (key <= qglob) ? sv : -3.0e38f;
          }
          p[ss * 4 + r] = sv;
          pm = fmaxf(pm, sv);
        }
      }
      pm = fmaxf(pm, __shfl_xor(pm, 16));
      pm = fmaxf(pm, __shfl_xor(pm, 32));
      const float m_new = fmaxf(m_run[qi], pm);
      const float alpha = EXP2(m_run[qi] - m_new);
      float lsum = 0.f;
      #pragma unroll
      for (int i = 0; i < 16; ++i) { float e = EXP2(p[i] - m_new); p[i] = e; lsum += e; }
      lsum += __shfl_xor(lsum, 16);
      lsum += __shfl_xor(lsum, 32);
      l_run[qi] = l_run[qi] * alpha + lsum;
      m_run[qi] = m_new;
      #pragma unroll
      for (int dt = 0; dt < 8; ++dt) o[qi][dt] *= alpha;
      // P[q][key] -> LDS (b64 writes; b128 reads below)
      #pragma unroll
      for (int ss = 0; ss < 4; ++ss) {
        unsigned w0 = ((unsigned)f2b(p[ss * 4 + 1]) << 16) | f2b(p[ss * 4 + 0]);
        unsigned w1 = ((unsigned)f2b(p[ss * 4 + 3]) << 16) | f2b(p[ss * 4 + 2]);
        uint2 u; u.x = w0; u.y = w1;
        *(uint2*)&plds[(qi * 16 + l16) * PST + ss * 16 + g4 * 4] = u;
      }
    }
    // PV B-operand: lane holds P[col=l16][k=ks*32+g4*8+j]
    bf16x8 pf[2][2];
    #pragma unroll
    for (int qi = 0; qi < 2; ++qi)
      #pragma unroll
      for (int ks = 0; ks < 2; ++ks)
        pf[qi][ks] = *(const bf16x8*)&plds[(qi * 16 + l16) * PST + ks * 32 + g4 * 8];

    // O^T[d][q] += sum_key V^T[d][key] * P[q][key]
    #pragma unroll
    for (int dt = 0; dt < 8; ++dt) {
      const unsigned short* vr = vp + (size_t)(dt * 16 + l16) * T_ + kv0;
      bf16x8 vf0 = *(const bf16x8*)(vr + g4 * 8);
      bf16x8 vf1 = *(const bf16x8*)(vr + 32 + g4 * 8);
      #pragma unroll
      for (int qi = 0; qi < 2; ++qi) {
        o[qi][dt] = __builtin_amdgcn_mfma_f32_16x16x32_bf16(vf0, pf[qi][0], o[qi][dt], 0, 0, 0);
        o[qi][dt] = __builtin_amdgcn_mfma_f32_16x16x32_bf16(vf1, pf[qi][1], o[qi][dt], 0, 0, 0);
      }
    }
  }

  #pragma unroll
  for (int qi = 0; qi < 2; ++qi) {
    const float inv_l = 1.0f / l_run[qi];
    unsigned short* yrow = Yb + ((size_t)(b * T_ + t0 + qi * 16 + l16) * CEMB) + h * D_;
    #pragma unroll
    for (int dt = 0; dt < 8; ++dt) {
      uint2 u;
      u.x = ((unsigned)f2b(o[qi][dt][1] * inv_l) << 16) | f2b(o[qi][dt][0] * inv_l);
      u.y = ((unsigned)f2b(o[qi][dt][3] * inv_l) << 16) | f2b(o[qi][dt][2] * inv_l);
      *(uint2*)(yrow + dt * 16 + g4 * 4) = u;
    }
  }
}

// ---------------------------------------------------------------------------
extern "C" void kernel_launch(void* const* d_in, const int* in_sizes, int n_in,
                              void* d_out, int out_size, void* d_ws, size_t ws_size,
                              hipStream_t stream) {
  const float* x    = (const float*)d_in[0];
  const float* cosp = (const float*)d_in[1];
  const float* sinp = (const float*)d_in[2];
  const float* Wq   = (const float*)d_in[3];
  const float* Wk   = (const float*)d_in[4];
  const float* Wv   = (const float*)d_in[5];
  const float* Wo   = (const float*)d_in[6];
  float* out = (float*)d_out;

  char* ws = (char*)d_ws;
  size_t off = 0;
  auto alloc = [&](size_t bytes) {
    void* p = ws + off;
    off += (bytes + 255) & ~(size_t)255;
    return p;
  };
  const size_t MT = (size_t)B_ * T_;  // 4096
  unsigned short* xb  = (unsigned short*)alloc(MT * CEMB * 2);
  unsigned short* wqb = (unsigned short*)alloc((size_t)2048 * 2048 * 2);
  unsigned short* wkb = (unsigned short*)alloc((size_t)512 * 2048 * 2);
  unsigned short* wvb = (unsigned short*)alloc((size_t)512 * 2048 * 2);
  unsigned short* wob = (unsigned short*)alloc((size_t)2048 * 2048 * 2);
  float* qf = (float*)alloc(MT * 2048 * 4);
  float* kf = (float*)alloc(MT * 512 * 4);
  float* vf = (float*)alloc(MT * 512 * 4);
  unsigned short* qn = (unsigned short*)alloc((size_t)B_ * H_ * T_ * D_ * 2);
  unsigned short* kn = (unsigned short*)alloc((size_t)B_ * HKV_ * T_ * D_ * 2);
  unsigned short* vt = (unsigned short*)alloc((size_t)B_ * HKV_ * D_ * T_ * 2);
  unsigned short* yb = (unsigned short*)alloc(MT * CEMB * 2);

  // bf16 casts
  cvt_kernel<<<2048, 256, 0, stream>>>(x,  xb,  (int)(MT * CEMB / 4));
  cvt_kernel<<<1024, 256, 0, stream>>>(Wq, wqb, 2048 * 2048 / 4);
  cvt_kernel<<<256,  256, 0, stream>>>(Wk, wkb, 512 * 2048 / 4);
  cvt_kernel<<<256,  256, 0, stream>>>(Wv, wvb, 512 * 2048 / 4);
  cvt_kernel<<<1024, 256, 0, stream>>>(Wo, wob, 2048 * 2048 / 4);

  // projections (C = x @ W^T)
  gemm_bt<<<dim3(2048 / BN, 4096 / BM), 256, 0, stream>>>(xb, wqb, qf, 4096, 2048, 2048);
  gemm_bt<<<dim3(512 / BN,  4096 / BM), 256, 0, stream>>>(xb, wkb, kf, 4096, 512, 2048);
  gemm_bt<<<dim3(512 / BN,  4096 / BM), 256, 0, stream>>>(xb, wvb, vf, 4096, 512, 2048);

  // RoPE + RMSNorm; Q gets (1/sqrt(D))*log2(e) folded in (softmax in exp2 domain)
  rope_norm<<<4096 * H_,  128, 0, stream>>>(qf, cosp, sinp, qn, H_,  0.1275174324f);
  rope_norm<<<4096 * HKV_, 128, 0, stream>>>(kf, cosp, sinp, kn, HKV_, 1.0f);
  vtrans<<<dim3(T_ / 64, D_ / 32, B_ * HKV_), 256, 0, stream>>>(vf, vt);

  // causal flash attention: 32 Q rows per wave, 64 keys per iter
  attn_kernel<<<dim3(T_ / 32, B_ * H_), 64, 0, stream>>>(qn, kn, vt, yb);

  // output projection -> f32 d_out
  gemm_bt<<<dim3(2048 / BN, 4096 / BM), 256, 0, stream>>>(yb, wob, out, 4096, 2048, 2048);
}

// Round 3
// 287.844 us; speedup vs baseline: 2.3092x; 1.5486x over previous
//
#include <hip/hip_runtime.h>
#include <hip/hip_bf16.h>
#include <stdint.h>

#define B_   2
#define T_   2048
#define CEMB 2048
#define H_   16
#define HKV_ 4
#define D_   128

typedef __attribute__((ext_vector_type(8))) short bf16x8;   // 8 x bf16 (4 VGPR)
typedef __attribute__((ext_vector_type(4))) float f32x4;    // MFMA 16x16 accumulator

#if __has_builtin(__builtin_amdgcn_exp2f)
#define EXP2(x) __builtin_amdgcn_exp2f(x)
#else
#define EXP2(x) exp2f(x)
#endif

__device__ __forceinline__ unsigned short f2b(float f) {
  union { float f; unsigned u; } v; v.f = f;
  unsigned r = v.u + 0x7FFFu + ((v.u >> 16) & 1u);   // RNE
  return (unsigned short)(r >> 16);
}
__device__ __forceinline__ float b2f(unsigned short u) {
  union { unsigned u; float f; } v; v.u = ((unsigned)u) << 16; return v.f;
}

// async global->LDS, 16B per lane; LDS dest = wave-uniform base + lane*16
__device__ __forceinline__ void gl16(const void* g, void* l) {
  __builtin_amdgcn_global_load_lds(
      (const __attribute__((address_space(1))) unsigned int*)g,
      (__attribute__((address_space(3))) unsigned int*)l, 16, 0, 0);
}

// ---------------- f32 -> bf16 convert (vectorized) ----------------
__global__ void cvt_kernel(const float* __restrict__ src,
                           unsigned short* __restrict__ dst, int n4) {
  int i = blockIdx.x * blockDim.x + threadIdx.x;
  const int stride = gridDim.x * blockDim.x;
  for (; i < n4; i += stride) {
    float4 v = ((const float4*)src)[i];
    ushort4 o;
    o.x = f2b(v.x); o.y = f2b(v.y); o.z = f2b(v.z); o.w = f2b(v.w);
    ((ushort4*)dst)[i] = o;
  }
}

// ---------------- GEMM: C[M][N] = A[M][K] (bf16) * W[N][K]^T (bf16) ----------
// m97 structure: global_load_lds(16B) staging, linear LDS, 2-barrier K-step.
#define BM 128
#define BN 128
#define BK 32

__global__ __launch_bounds__(256)
void gemm_bt(const unsigned short* __restrict__ A,
             const unsigned short* __restrict__ W,
             void* __restrict__ Cmat, int M, int N, int K, int obf16) {
  __shared__ alignas(16) unsigned short As[BM * BK];
  __shared__ alignas(16) unsigned short Ws[BN * BK];

  const int tid  = threadIdx.x;
  const int lane = tid & 63;
  const int wv   = tid >> 6;
  const int wr   = wv >> 1, wc = wv & 1;      // 2x2 wave grid, 64x64 each
  const int l16  = lane & 15, g4 = lane >> 4;
  const int m0 = blockIdx.y * BM;
  const int n0 = blockIdx.x * BN;

  f32x4 acc[4][4] = {};

  const unsigned short* Aptr = A + (size_t)m0 * K;
  const unsigned short* Wptr = W + (size_t)n0 * K;

  // staging decomposition: per instr 64 lanes x 16B = 16 rows of 64B
  const int srow = lane >> 2;      // 0..15
  const int schk = lane & 3;       // 16B chunk in a 32-elem row

  const int nk = K / BK;
  for (int kt = 0; kt < nk; ++kt) {
    const int k0 = kt * BK;
    __syncthreads();               // all waves done reading LDS from prev iter
    #pragma unroll
    for (int j = 0; j < 2; ++j) {
      const int row0 = wv * 32 + j * 16;
      gl16(Aptr + (size_t)(row0 + srow) * K + k0 + schk * 8, &As[row0 * BK]);
      gl16(Wptr + (size_t)(row0 + srow) * K + k0 + schk * 8, &Ws[row0 * BK]);
    }
    __syncthreads();               // vmcnt drained -> tile visible
    bf16x8 af[4], wf[4];
    #pragma unroll
    for (int mi = 0; mi < 4; ++mi) {
      int ar = wr * 64 + mi * 16 + l16;
      af[mi] = *(const bf16x8*)&As[ar * BK + g4 * 8];
    }
    #pragma unroll
    for (int ni = 0; ni < 4; ++ni) {
      int wrw = wc * 64 + ni * 16 + l16;
      wf[ni] = *(const bf16x8*)&Ws[wrw * BK + g4 * 8];
    }
    #pragma unroll
    for (int mi = 0; mi < 4; ++mi) {
      #pragma unroll
      for (int ni = 0; ni < 4; ++ni) {
        acc[mi][ni] = __builtin_amdgcn_mfma_f32_16x16x32_bf16(
            af[mi], wf[ni], acc[mi][ni], 0, 0, 0);
      }
    }
  }

  // epilogue: C/D layout col = lane&15, row = (lane>>4)*4 + reg
  #pragma unroll
  for (int mi = 0; mi < 4; ++mi) {
    #pragma unroll
    for (int ni = 0; ni < 4; ++ni) {
      const int row = m0 + wr * 64 + mi * 16 + g4 * 4;
      const int col = n0 + wc * 64 + ni * 16 + l16;
      if (obf16) {
        unsigned short* Cb = (unsigned short*)Cmat;
        #pragma unroll
        for (int r = 0; r < 4; ++r)
          Cb[(size_t)(row + r) * N + col] = f2b(acc[mi][ni][r]);
      } else {
        float* Cf = (float*)Cmat;
        #pragma unroll
        for (int r = 0; r < 4; ++r)
          Cf[(size_t)(row + r) * N + col] = acc[mi][ni][r];
      }
    }
  }
}

// ---------------- fused RoPE + RMSNorm (bf16 in) + [B,H,T,D] bf16 out --------
__global__ __launch_bounds__(128)
void rope_norm(const unsigned short* __restrict__ X, int rstride,
               const float* __restrict__ Cos, const float* __restrict__ Sin,
               unsigned short* __restrict__ Out, int Hn, float out_scale) {
  const int idx = blockIdx.x;
  const int h  = idx % Hn;
  const int bt = idx / Hn;
  const int t  = bt & (T_ - 1);
  const int b  = bt >> 11;
  const int d  = threadIdx.x;        // 0..127
  const unsigned short* src = X + (size_t)bt * rstride + h * D_;
  float y;
  if (d < 64) {
    float x1 = b2f(src[d]), x2 = b2f(src[d + 64]);
    float c = Cos[t * 64 + d], s = Sin[t * 64 + d];
    y = x1 * c + x2 * s;
  } else {
    int dd = d - 64;
    float x1 = b2f(src[dd]), x2 = b2f(src[d]);
    float c = Cos[t * 64 + dd], s = Sin[t * 64 + dd];
    y = -x1 * s + x2 * c;
  }
  float ss = y * y;
  #pragma unroll
  for (int m = 32; m; m >>= 1) ss += __shfl_xor(ss, m);
  __shared__ float red[2];
  if ((d & 63) == 0) red[d >> 6] = ss;
  __syncthreads();
  const float tot  = red[0] + red[1];
  const float rinv = rsqrtf(tot * (1.0f / 128.0f) + 1.1920929e-7f) * out_scale;
  Out[(((size_t)b * Hn + h) * T_ + t) * D_ + d] = f2b(y * rinv);
}

// ---------------- V: [B,T,*,D] bf16 (strided) -> [B,HKV,D,T] bf16 ------------
__global__ __launch_bounds__(256)
void vtrans(const unsigned short* __restrict__ Vf, int rstride,
            unsigned short* __restrict__ Vt) {
  __shared__ float tile[32][65];
  const int t0 = blockIdx.x * 64;
  const int d0 = blockIdx.y * 32;
  const int bh = blockIdx.z;
  const int b = bh >> 2, hk = bh & 3;
  const int tid = threadIdx.x;
  {
    const int di = tid & 31, ts = tid >> 5;
    #pragma unroll
    for (int i = 0; i < 8; ++i) {
      int tt = ts + i * 8;
      tile[di][tt] = b2f(Vf[(size_t)(b * T_ + t0 + tt) * rstride + hk * D_ + d0 + di]);
    }
  }
  __syncthreads();
  {
    const int ti = tid & 63, ds = tid >> 6;
    #pragma unroll
    for (int i = 0; i < 8; ++i) {
      int dd = ds * 8 + i;
      Vt[((size_t)bh * D_ + d0 + dd) * T_ + t0 + ti] = f2b(tile[dd][ti]);
    }
  }
}

// ---------------- flash attention, causal, 4-wave cooperative ----------------
// Block: 4 waves, 128 Q rows (32/wave). KVBLK=64. K/V^T double-buffered in LDS
// via global_load_lds with swizzled per-lane source (linear LDS dest).
// Qn: [B,H,T,D] pre-scaled by (1/sqrt(D))*log2(e); Kn: [B,HKV,T,D]; Vt: [B,HKV,D,T]
#define KVB 64

__global__ __launch_bounds__(256, 2)
void attn_kernel(const unsigned short* __restrict__ Qn,
                 const unsigned short* __restrict__ Kn,
                 const unsigned short* __restrict__ Vt,
                 unsigned short* __restrict__ Yb) {
  __shared__ alignas(16) unsigned short Ks[2][KVB * D_];   // [key][chunk^(key&7)]
  __shared__ alignas(16) unsigned short Vs[2][D_ * KVB];   // V^T [d][chunk^(d&7)]
  __shared__ alignas(16) unsigned short plds[4 * 2 * 16 * 64];

  const int tid = threadIdx.x;
  const int lane = tid & 63;
  const int w = tid >> 6;
  const int l16 = lane & 15, g4 = lane >> 4;
  const int qt = blockIdx.x;
  const int bh = blockIdx.y;
  const int b = bh >> 4, h = bh & 15;
  const int hk = h >> 2;                  // GQA: 4 q-heads per kv-head
  const int t0 = qt * 128;
  const int qrow0 = t0 + w * 32;
  const int qmax = qrow0 + 31;

  const unsigned short* qp = Qn + ((size_t)bh * T_ + qrow0) * D_;
  const unsigned short* kp = Kn + ((size_t)(b * HKV_ + hk) * T_) * D_;
  const unsigned short* vp = Vt + ((size_t)(b * HKV_ + hk) * D_) * T_;
  unsigned short* pw = plds + w * 2048;   // per-wave P region

  bf16x8 qf[2][4];
  #pragma unroll
  for (int qi = 0; qi < 2; ++qi)
    #pragma unroll
    for (int kq = 0; kq < 4; ++kq)
      qf[qi][kq] = *(const bf16x8*)(qp + (size_t)(qi * 16 + l16) * D_ + kq * 32 + g4 * 8);

  f32x4 o[2][8] = {};
  float m_run[2] = {-3.0e38f, -3.0e38f};
  float l_run[2] = {0.f, 0.f};

  // staging lane decomposition
  const int kr4 = lane >> 4, kc = lane & 15;   // K: 4 rows (256B) per instr
  const int vr8 = lane >> 3, vc = lane & 7;    // V: 8 rows (128B) per instr

  const int nt = qt * 2 + 2;

  // prologue: stage tile 0 into buf 0
  {
    #pragma unroll
    for (int j = 0; j < 4; ++j) {
      int key = w * 16 + j * 4 + kr4;
      int cg = kc ^ (key & 7);
      gl16(kp + (size_t)key * D_ + cg * 8, &Ks[0][(w * 16 + j * 4) * D_]);
    }
    #pragma unroll
    for (int j = 0; j < 4; ++j) {
      int d = w * 32 + j * 8 + vr8;
      int cg = vc ^ (d & 7);
      gl16(vp + (size_t)d * T_ + cg * 8, &Vs[0][(w * 32 + j * 8) * KVB]);
    }
  }

  for (int t = 0; t < nt; ++t) {
    __syncthreads();   // drains vmcnt(0): buf[t&1] staged; prev compute done
    if (t + 1 < nt) {  // stage next tile into other buffer (hides under compute)
      const int kv1 = (t + 1) * KVB;
      #pragma unroll
      for (int j = 0; j < 4; ++j) {
        int key = w * 16 + j * 4 + kr4;
        int cg = kc ^ (key & 7);
        gl16(kp + (size_t)(kv1 + key) * D_ + cg * 8, &Ks[(t + 1) & 1][(w * 16 + j * 4) * D_]);
      }
      #pragma unroll
      for (int j = 0; j < 4; ++j) {
        int d = w * 32 + j * 8 + vr8;
        int cg = vc ^ (d & 7);
        gl16(vp + (size_t)d * T_ + kv1 + cg * 8, &Vs[(t + 1) & 1][(w * 32 + j * 8) * KVB]);
      }
    }
    const int kv0 = t * KVB;
    if (kv0 <= qmax) {
      const unsigned short* kb = Ks[t & 1];
      const unsigned short* vb = Vs[t & 1];
      // S^T[key][q] = sum_d K[key][d]*Q[q][d]
      f32x4 sacc[2][4] = {};
      #pragma unroll
      for (int ss = 0; ss < 4; ++ss) {
        const int key = ss * 16 + l16;
        bf16x8 kf[4];
        #pragma unroll
        for (int kq = 0; kq < 4; ++kq) {
          int sc = (kq * 4 + g4) ^ (key & 7);
          kf[kq] = *(const bf16x8*)(kb + key * D_ + sc * 8);
        }
        #pragma unroll
        for (int qi = 0; qi < 2; ++qi)
          #pragma unroll
          for (int kq = 0; kq < 4; ++kq)
            sacc[qi][ss] = __builtin_amdgcn_mfma_f32_16x16x32_bf16(
                kf[kq], qf[qi][kq], sacc[qi][ss], 0, 0, 0);
      }
      const bool need_mask = (kv0 + KVB - 1 > qrow0);
      #pragma unroll
      for (int qi = 0; qi < 2; ++qi) {
        const int qglob = qrow0 + qi * 16 + l16;
        float p[16];
        float pm = -3.0e38f;
        #pragma unroll
        for (int ss = 0; ss < 4; ++ss) {
          #pragma unroll
          for (int r = 0; r < 4; ++r) {
            float sv = sacc[qi][ss][r];
            if (need_mask) {
              int key = kv0 + ss * 16 + g4 * 4 + r;
              sv = (key <= qglob) ? sv : -3.0e38f;
            }
            p[ss * 4 + r] = sv;
            pm = fmaxf(pm, sv);
          }
        }
        pm = fmaxf(pm, __shfl_xor(pm, 16));
        pm = fmaxf(pm, __shfl_xor(pm, 32));
        const float m_new = fmaxf(m_run[qi], pm);
        const float alpha = EXP2(m_run[qi] - m_new);
        float lsum = 0.f;
        #pragma unroll
        for (int i = 0; i < 16; ++i) { float e = EXP2(p[i] - m_new); p[i] = e; lsum += e; }
        lsum += __shfl_xor(lsum, 16);
        lsum += __shfl_xor(lsum, 32);
        l_run[qi] = l_run[qi] * alpha + lsum;
        m_run[qi] = m_new;
        #pragma unroll
        for (int dt = 0; dt < 8; ++dt) o[qi][dt] *= alpha;
        // P[q][key] -> per-wave LDS, swizzled 16B chunks: sc = ch ^ (row&7)
        #pragma unroll
        for (int ss = 0; ss < 4; ++ss) {
          unsigned w0 = ((unsigned)f2b(p[ss * 4 + 1]) << 16) | f2b(p[ss * 4 + 0]);
          unsigned w1 = ((unsigned)f2b(p[ss * 4 + 3]) << 16) | f2b(p[ss * 4 + 2]);
          uint2 u; u.x = w0; u.y = w1;
          int ch = ss * 2 + (g4 >> 1);
          int sc = ch ^ (l16 & 7);
          *(uint2*)&pw[qi * 1024 + l16 * 64 + sc * 8 + (g4 & 1) * 4] = u;
        }
      }
      // PV: O^T[d][q] += sum_key V^T[d][key] * P[q][key]
      bf16x8 pf[2][2];
      #pragma unroll
      for (int qi = 0; qi < 2; ++qi)
        #pragma unroll
        for (int ks = 0; ks < 2; ++ks) {
          int sc = (ks * 4 + g4) ^ (l16 & 7);
          pf[qi][ks] = *(const bf16x8*)&pw[qi * 1024 + l16 * 64 + sc * 8];
        }
      #pragma unroll
      for (int dt = 0; dt < 8; ++dt) {
        const int d = dt * 16 + l16;
        int sc0 = (0 * 4 + g4) ^ (d & 7);
        int sc1 = (1 * 4 + g4) ^ (d & 7);
        bf16x8 vf0 = *(const bf16x8*)(vb + d * KVB + sc0 * 8);
        bf16x8 vf1 = *(const bf16x8*)(vb + d * KVB + sc1 * 8);
        #pragma unroll
        for (int qi = 0; qi < 2; ++qi) {
          o[qi][dt] = __builtin_amdgcn_mfma_f32_16x16x32_bf16(vf0, pf[qi][0], o[qi][dt], 0, 0, 0);
          o[qi][dt] = __builtin_amdgcn_mfma_f32_16x16x32_bf16(vf1, pf[qi][1], o[qi][dt], 0, 0, 0);
        }
      }
    }
  }

  #pragma unroll
  for (int qi = 0; qi < 2; ++qi) {
    const float inv_l = 1.0f / l_run[qi];
    unsigned short* yrow = Yb + ((size_t)(b * T_ + qrow0 + qi * 16 + l16) * CEMB) + h * D_;
    #pragma unroll
    for (int dt = 0; dt < 8; ++dt) {
      uint2 u;
      u.x = ((unsigned)f2b(o[qi][dt][1] * inv_l) << 16) | f2b(o[qi][dt][0] * inv_l);
      u.y = ((unsigned)f2b(o[qi][dt][3] * inv_l) << 16) | f2b(o[qi][dt][2] * inv_l);
      *(uint2*)(yrow + dt * 16 + g4 * 4) = u;
    }
  }
}

// ---------------------------------------------------------------------------
extern "C" void kernel_launch(void* const* d_in, const int* in_sizes, int n_in,
                              void* d_out, int out_size, void* d_ws, size_t ws_size,
                              hipStream_t stream) {
  const float* x    = (const float*)d_in[0];
  const float* cosp = (const float*)d_in[1];
  const float* sinp = (const float*)d_in[2];
  const float* Wq   = (const float*)d_in[3];
  const float* Wk   = (const float*)d_in[4];
  const float* Wv   = (const float*)d_in[5];
  const float* Wo   = (const float*)d_in[6];
  float* out = (float*)d_out;

  char* ws = (char*)d_ws;
  size_t off = 0;
  auto alloc = [&](size_t bytes) {
    void* p = ws + off;
    off += (bytes + 255) & ~(size_t)255;
    return p;
  };
  const size_t MT = (size_t)B_ * T_;  // 4096
  const int NQKV = 3072;              // 2048 q + 512 k + 512 v
  unsigned short* xb    = (unsigned short*)alloc(MT * CEMB * 2);
  unsigned short* wqkvb = (unsigned short*)alloc((size_t)NQKV * 2048 * 2);
  unsigned short* wob   = (unsigned short*)alloc((size_t)2048 * 2048 * 2);
  unsigned short* qkvb  = (unsigned short*)alloc(MT * NQKV * 2);
  unsigned short* qn    = (unsigned short*)alloc((size_t)B_ * H_ * T_ * D_ * 2);
  unsigned short* kn    = (unsigned short*)alloc((size_t)B_ * HKV_ * T_ * D_ * 2);
  unsigned short* vt    = (unsigned short*)alloc((size_t)B_ * HKV_ * D_ * T_ * 2);
  unsigned short* yb    = (unsigned short*)alloc(MT * CEMB * 2);

  // bf16 casts (weights concatenated into [3072][2048])
  cvt_kernel<<<2048, 256, 0, stream>>>(x,  xb, (int)(MT * CEMB / 4));
  cvt_kernel<<<1024, 256, 0, stream>>>(Wq, wqkvb,                2048 * 2048 / 4);
  cvt_kernel<<<256,  256, 0, stream>>>(Wk, wqkvb + 2048 * 2048,  512 * 2048 / 4);
  cvt_kernel<<<256,  256, 0, stream>>>(Wv, wqkvb + 2560 * 2048,  512 * 2048 / 4);
  cvt_kernel<<<1024, 256, 0, stream>>>(Wo, wob,                  2048 * 2048 / 4);

  // fused QKV projection: [4096][3072] bf16
  gemm_bt<<<dim3(NQKV / BN, 4096 / BM), 256, 0, stream>>>(xb, wqkvb, qkvb, 4096, NQKV, 2048, 1);

  // RoPE + RMSNorm; Q gets (1/sqrt(D))*log2(e) folded (softmax in exp2 domain)
  rope_norm<<<4096 * H_,   128, 0, stream>>>(qkvb,        NQKV, cosp, sinp, qn, H_,   0.1275174324f);
  rope_norm<<<4096 * HKV_, 128, 0, stream>>>(qkvb + 2048, NQKV, cosp, sinp, kn, HKV_, 1.0f);
  vtrans<<<dim3(T_ / 64, D_ / 32, B_ * HKV_), 256, 0, stream>>>(qkvb + 2560, NQKV, vt);

  // causal flash attention: 4-wave blocks, 128 Q rows each
  attn_kernel<<<dim3(T_ / 128, B_ * H_), 256, 0, stream>>>(qn, kn, vt, yb);

  // output projection -> f32 d_out
  gemm_bt<<<dim3(2048 / BN, 4096 / BM), 256, 0, stream>>>(yb, wob, out, 4096, 2048, 2048, 0);
}

// Round 4
// 262.871 us; speedup vs baseline: 2.5286x; 1.0950x over previous
//
#include <hip/hip_runtime.h>
#include <hip/hip_bf16.h>
#include <stdint.h>

#define B_   2
#define T_   2048
#define CEMB 2048
#define H_   16
#define HKV_ 4
#define D_   128

typedef __attribute__((ext_vector_type(8))) short bf16x8;   // 8 x bf16 (4 VGPR)
typedef __attribute__((ext_vector_type(4))) float f32x4;    // MFMA 16x16 accumulator

#if __has_builtin(__builtin_amdgcn_exp2f)
#define EXP2(x) __builtin_amdgcn_exp2f(x)
#else
#define EXP2(x) exp2f(x)
#endif

__device__ __forceinline__ unsigned short f2b(float f) {
  union { float f; unsigned u; } v; v.f = f;
  unsigned r = v.u + 0x7FFFu + ((v.u >> 16) & 1u);   // RNE
  return (unsigned short)(r >> 16);
}
__device__ __forceinline__ float b2f(unsigned short u) {
  union { unsigned u; float f; } v; v.u = ((unsigned)u) << 16; return v.f;
}
// pack 2 f32 -> 2 bf16 (RNE), single instruction
__device__ __forceinline__ unsigned cvtpk(float lo, float hi) {
  unsigned r;
  asm("v_cvt_pk_bf16_f32 %0, %1, %2" : "=v"(r) : "v"(lo), "v"(hi));
  return r;
}

// async global->LDS, 16B per lane; LDS dest = wave-uniform base + lane*16
__device__ __forceinline__ void gl16(const void* g, void* l) {
  __builtin_amdgcn_global_load_lds(
      (const __attribute__((address_space(1))) unsigned int*)g,
      (__attribute__((address_space(3))) unsigned int*)l, 16, 0, 0);
}

// ---------------- f32 -> bf16 convert (vectorized) ----------------
__global__ void cvt_kernel(const float* __restrict__ src,
                           unsigned short* __restrict__ dst, int n4) {
  int i = blockIdx.x * blockDim.x + threadIdx.x;
  const int stride = gridDim.x * blockDim.x;
  for (; i < n4; i += stride) {
    float4 v = ((const float4*)src)[i];
    ushort4 o;
    o.x = f2b(v.x); o.y = f2b(v.y); o.z = f2b(v.z); o.w = f2b(v.w);
    ((ushort4*)dst)[i] = o;
  }
}

// ---------------- GEMM: C[M][N] = A[M][K] (bf16) * W[N][K]^T (bf16) ----------
// m97 structure + XCD-aware block swizzle (requires nwg % 8 == 0).
#define BM 128
#define BN 128
#define BK 32

__global__ __launch_bounds__(256)
void gemm_bt(const unsigned short* __restrict__ A,
             const unsigned short* __restrict__ W,
             void* __restrict__ Cmat, int M, int N, int K, int obf16) {
  __shared__ alignas(16) unsigned short As[BM * BK];
  __shared__ alignas(16) unsigned short Ws[BN * BK];

  const int tid  = threadIdx.x;
  const int lane = tid & 63;
  const int wv   = tid >> 6;
  const int wr   = wv >> 1, wc = wv & 1;      // 2x2 wave grid, 64x64 each
  const int l16  = lane & 15, g4 = lane >> 4;

  // XCD-aware swizzle: contiguous swz range per XCD -> A-panel L2 reuse
  const int gx  = gridDim.x;
  const int nwg = gx * gridDim.y;
  const int lin = blockIdx.y * gx + blockIdx.x;
  const int cpx = nwg >> 3;
  const int swz = (lin & 7) * cpx + (lin >> 3);
  const int m0 = (swz / gx) * BM;
  const int n0 = (swz % gx) * BN;

  f32x4 acc[4][4] = {};

  const unsigned short* Aptr = A + (size_t)m0 * K;
  const unsigned short* Wptr = W + (size_t)n0 * K;

  const int srow = lane >> 2;      // 0..15
  const int schk = lane & 3;       // 16B chunk in a 32-elem row

  const int nk = K / BK;
  for (int kt = 0; kt < nk; ++kt) {
    const int k0 = kt * BK;
    __syncthreads();
    #pragma unroll
    for (int j = 0; j < 2; ++j) {
      const int row0 = wv * 32 + j * 16;
      gl16(Aptr + (size_t)(row0 + srow) * K + k0 + schk * 8, &As[row0 * BK]);
      gl16(Wptr + (size_t)(row0 + srow) * K + k0 + schk * 8, &Ws[row0 * BK]);
    }
    __syncthreads();
    bf16x8 af[4], wf[4];
    #pragma unroll
    for (int mi = 0; mi < 4; ++mi) {
      int ar = wr * 64 + mi * 16 + l16;
      af[mi] = *(const bf16x8*)&As[ar * BK + g4 * 8];
    }
    #pragma unroll
    for (int ni = 0; ni < 4; ++ni) {
      int wrw = wc * 64 + ni * 16 + l16;
      wf[ni] = *(const bf16x8*)&Ws[wrw * BK + g4 * 8];
    }
    #pragma unroll
    for (int mi = 0; mi < 4; ++mi) {
      #pragma unroll
      for (int ni = 0; ni < 4; ++ni) {
        acc[mi][ni] = __builtin_amdgcn_mfma_f32_16x16x32_bf16(
            af[mi], wf[ni], acc[mi][ni], 0, 0, 0);
      }
    }
  }

  // epilogue: C/D layout col = lane&15, row = (lane>>4)*4 + reg
  #pragma unroll
  for (int mi = 0; mi < 4; ++mi) {
    #pragma unroll
    for (int ni = 0; ni < 4; ++ni) {
      const int row = m0 + wr * 64 + mi * 16 + g4 * 4;
      const int col = n0 + wc * 64 + ni * 16 + l16;
      if (obf16) {
        unsigned short* Cb = (unsigned short*)Cmat;
        #pragma unroll
        for (int r = 0; r < 4; ++r)
          Cb[(size_t)(row + r) * N + col] = f2b(acc[mi][ni][r]);
      } else {
        float* Cf = (float*)Cmat;
        #pragma unroll
        for (int r = 0; r < 4; ++r)
          Cf[(size_t)(row + r) * N + col] = acc[mi][ni][r];
      }
    }
  }
}

// ---------------- fused RoPE + RMSNorm (bf16 in) + [B,H,T,D] bf16 out --------
__global__ __launch_bounds__(128)
void rope_norm(const unsigned short* __restrict__ X, int rstride,
               const float* __restrict__ Cos, const float* __restrict__ Sin,
               unsigned short* __restrict__ Out, int Hn, float out_scale) {
  const int idx = blockIdx.x;
  const int h  = idx % Hn;
  const int bt = idx / Hn;
  const int t  = bt & (T_ - 1);
  const int b  = bt >> 11;
  const int d  = threadIdx.x;        // 0..127
  const unsigned short* src = X + (size_t)bt * rstride + h * D_;
  float y;
  if (d < 64) {
    float x1 = b2f(src[d]), x2 = b2f(src[d + 64]);
    float c = Cos[t * 64 + d], s = Sin[t * 64 + d];
    y = x1 * c + x2 * s;
  } else {
    int dd = d - 64;
    float x1 = b2f(src[dd]), x2 = b2f(src[d]);
    float c = Cos[t * 64 + dd], s = Sin[t * 64 + dd];
    y = -x1 * s + x2 * c;
  }
  float ss = y * y;
  #pragma unroll
  for (int m = 32; m; m >>= 1) ss += __shfl_xor(ss, m);
  __shared__ float red[2];
  if ((d & 63) == 0) red[d >> 6] = ss;
  __syncthreads();
  const float tot  = red[0] + red[1];
  const float rinv = rsqrtf(tot * (1.0f / 128.0f) + 1.1920929e-7f) * out_scale;
  Out[(((size_t)b * Hn + h) * T_ + t) * D_ + d] = f2b(y * rinv);
}

// ---------------- V: [B,T,*,D] bf16 (strided) -> [B,HKV,D,T] bf16 ------------
__global__ __launch_bounds__(256)
void vtrans(const unsigned short* __restrict__ Vf, int rstride,
            unsigned short* __restrict__ Vt) {
  __shared__ float tile[32][65];
  const int t0 = blockIdx.x * 64;
  const int d0 = blockIdx.y * 32;
  const int bh = blockIdx.z;
  const int b = bh >> 2, hk = bh & 3;
  const int tid = threadIdx.x;
  {
    const int di = tid & 31, ts = tid >> 5;
    #pragma unroll
    for (int i = 0; i < 8; ++i) {
      int tt = ts + i * 8;
      tile[di][tt] = b2f(Vf[(size_t)(b * T_ + t0 + tt) * rstride + hk * D_ + d0 + di]);
    }
  }
  __syncthreads();
  {
    const int ti = tid & 63, ds = tid >> 6;
    #pragma unroll
    for (int i = 0; i < 8; ++i) {
      int dd = ds * 8 + i;
      Vt[((size_t)bh * D_ + d0 + dd) * T_ + t0 + ti] = f2b(tile[dd][ti]);
    }
  }
}

// ---------------- flash attention, causal, 4-wave cooperative ----------------
// Pair-balanced: block processes q-tiles {15-p, p} sequentially = 34 tile-iters
// for every block. Fixed-shift softmax (RMSNorm bound |score*log2e| <= 16.33):
// P = exp2(S'), no max tracking, no rescale; l is a per-lane partial sum.
#define KVB 64

__global__ __launch_bounds__(256)
void attn_kernel(const unsigned short* __restrict__ Qn,
                 const unsigned short* __restrict__ Kn,
                 const unsigned short* __restrict__ Vt,
                 unsigned short* __restrict__ Yb) {
  __shared__ alignas(16) unsigned short Ks[2][KVB * D_];   // [key][chunk^(key&7)]
  __shared__ alignas(16) unsigned short Vs[2][D_ * KVB];   // V^T [d][chunk^(d&7)]
  __shared__ alignas(16) unsigned short plds[4 * 2 * 16 * 64];

  const int tid = threadIdx.x;
  const int lane = tid & 63;
  const int w = tid >> 6;
  const int l16 = lane & 15, g4 = lane >> 4;
  const int bh = blockIdx.x;              // bh-major: XCD KV working set = 4MB
  const int pr = blockIdx.y;              // pair index 0..7
  const int b = bh >> 4, h = bh & 15;
  const int hk = h >> 2;                  // GQA: 4 q-heads per kv-head

  const unsigned short* kp = Kn + ((size_t)(b * HKV_ + hk) * T_) * D_;
  const unsigned short* vp = Vt + ((size_t)(b * HKV_ + hk) * D_) * T_;
  unsigned short* pw = plds + w * 2048;   // per-wave P region

  // staging lane decomposition
  const int kr4 = lane >> 4, kc = lane & 15;   // K: 4 rows (256B) per instr
  const int vr8 = lane >> 3, vc = lane & 7;    // V: 8 rows (128B) per instr

  for (int pass = 0; pass < 2; ++pass) {
    const int qt = pass ? pr : 15 - pr;        // heavy tile first
    const int t0 = qt * 128;
    const int qrow0 = t0 + w * 32;
    const int qmax = qrow0 + 31;
    const int nt = qt * 2 + 2;

    const unsigned short* qp = Qn + ((size_t)bh * T_ + qrow0) * D_;
    bf16x8 qf[2][4];
    #pragma unroll
    for (int qi = 0; qi < 2; ++qi)
      #pragma unroll
      for (int kq = 0; kq < 4; ++kq)
        qf[qi][kq] = *(const bf16x8*)(qp + (size_t)(qi * 16 + l16) * D_ + kq * 32 + g4 * 8);

    f32x4 o[2][8] = {};
    float l_part[2] = {0.f, 0.f};

    // prologue: stage tile 0 into buf 0 (safe: buf0 not read by prev pass tail)
    {
      #pragma unroll
      for (int j = 0; j < 4; ++j) {
        int key = w * 16 + j * 4 + kr4;
        int cg = kc ^ (key & 7);
        gl16(kp + (size_t)key * D_ + cg * 8, &Ks[0][(w * 16 + j * 4) * D_]);
      }
      #pragma unroll
      for (int j = 0; j < 4; ++j) {
        int d = w * 32 + j * 8 + vr8;
        int cg = vc ^ (d & 7);
        gl16(vp + (size_t)d * T_ + cg * 8, &Vs[0][(w * 32 + j * 8) * KVB]);
      }
    }

    for (int t = 0; t < nt; ++t) {
      __syncthreads();   // drains vmcnt(0): buf[t&1] staged; prev compute done
      if (t + 1 < nt) {  // stage next tile into other buffer
        const int kv1 = (t + 1) * KVB;
        #pragma unroll
        for (int j = 0; j < 4; ++j) {
          int key = w * 16 + j * 4 + kr4;
          int cg = kc ^ (key & 7);
          gl16(kp + (size_t)(kv1 + key) * D_ + cg * 8, &Ks[(t + 1) & 1][(w * 16 + j * 4) * D_]);
        }
        #pragma unroll
        for (int j = 0; j < 4; ++j) {
          int d = w * 32 + j * 8 + vr8;
          int cg = vc ^ (d & 7);
          gl16(vp + (size_t)d * T_ + kv1 + cg * 8, &Vs[(t + 1) & 1][(w * 32 + j * 8) * KVB]);
        }
      }
      const int kv0 = t * KVB;
      if (kv0 <= qmax) {
        const unsigned short* kb = Ks[t & 1];
        const unsigned short* vb = Vs[t & 1];
        // S^T[key][q] = sum_d K[key][d]*Q[q][d]
        f32x4 sacc[2][4] = {};
        #pragma unroll
        for (int ss = 0; ss < 4; ++ss) {
          const int key = ss * 16 + l16;
          bf16x8 kf[4];
          #pragma unroll
          for (int kq = 0; kq < 4; ++kq) {
            int sc = (kq * 4 + g4) ^ (key & 7);
            kf[kq] = *(const bf16x8*)(kb + key * D_ + sc * 8);
          }
          #pragma unroll
          for (int qi = 0; qi < 2; ++qi)
            #pragma unroll
            for (int kq = 0; kq < 4; ++kq)
              sacc[qi][ss] = __builtin_amdgcn_mfma_f32_16x16x32_bf16(
                  kf[kq], qf[qi][kq], sacc[qi][ss], 0, 0, 0);
        }
        const bool need_mask = (kv0 + KVB - 1 > qrow0);
        #pragma unroll
        for (int qi = 0; qi < 2; ++qi) {
          const int qglob = qrow0 + qi * 16 + l16;
          float p[16];
          float ls = 0.f;
          #pragma unroll
          for (int ss = 0; ss < 4; ++ss) {
            #pragma unroll
            for (int r = 0; r < 4; ++r) {
              float e = EXP2(sacc[qi][ss][r]);   // bounded: |arg| <= 16.33
              if (need_mask) {
                int key = kv0 + ss * 16 + g4 * 4 + r;
                e = (key <= qglob) ? e : 0.f;
              }
              p[ss * 4 + r] = e;
              ls += e;
            }
          }
          l_part[qi] += ls;
          // P[q][key] -> per-wave LDS, swizzled 16B chunks: sc = ch ^ (row&7)
          #pragma unroll
          for (int ss = 0; ss < 4; ++ss) {
            uint2 u;
            u.x = cvtpk(p[ss * 4 + 0], p[ss * 4 + 1]);
            u.y = cvtpk(p[ss * 4 + 2], p[ss * 4 + 3]);
            int ch = ss * 2 + (g4 >> 1);
            int sc = ch ^ (l16 & 7);
            *(uint2*)&pw[qi * 1024 + l16 * 64 + sc * 8 + (g4 & 1) * 4] = u;
          }
        }
        // PV: O^T[d][q] += sum_key V^T[d][key] * P[q][key]
        bf16x8 pf[2][2];
        #pragma unroll
        for (int qi = 0; qi < 2; ++qi)
          #pragma unroll
          for (int ks = 0; ks < 2; ++ks) {
            int sc = (ks * 4 + g4) ^ (l16 & 7);
            pf[qi][ks] = *(const bf16x8*)&pw[qi * 1024 + l16 * 64 + sc * 8];
          }
        #pragma unroll
        for (int dt = 0; dt < 8; ++dt) {
          const int d = dt * 16 + l16;
          int sc0 = (0 * 4 + g4) ^ (d & 7);
          int sc1 = (1 * 4 + g4) ^ (d & 7);
          bf16x8 vf0 = *(const bf16x8*)(vb + d * KVB + sc0 * 8);
          bf16x8 vf1 = *(const bf16x8*)(vb + d * KVB + sc1 * 8);
          #pragma unroll
          for (int qi = 0; qi < 2; ++qi) {
            o[qi][dt] = __builtin_amdgcn_mfma_f32_16x16x32_bf16(vf0, pf[qi][0], o[qi][dt], 0, 0, 0);
            o[qi][dt] = __builtin_amdgcn_mfma_f32_16x16x32_bf16(vf1, pf[qi][1], o[qi][dt], 0, 0, 0);
          }
        }
      }
    }

    #pragma unroll
    for (int qi = 0; qi < 2; ++qi) {
      float lsum = l_part[qi];
      lsum += __shfl_xor(lsum, 16);
      lsum += __shfl_xor(lsum, 32);
      const float inv_l = 1.0f / lsum;
      unsigned short* yrow = Yb + ((size_t)(b * T_ + qrow0 + qi * 16 + l16) * CEMB) + h * D_;
      #pragma unroll
      for (int dt = 0; dt < 8; ++dt) {
        uint2 u;
        u.x = cvtpk(o[qi][dt][0] * inv_l, o[qi][dt][1] * inv_l);
        u.y = cvtpk(o[qi][dt][2] * inv_l, o[qi][dt][3] * inv_l);
        *(uint2*)(yrow + dt * 16 + g4 * 4) = u;
      }
    }
  }
}

// ---------------------------------------------------------------------------
extern "C" void kernel_launch(void* const* d_in, const int* in_sizes, int n_in,
                              void* d_out, int out_size, void* d_ws, size_t ws_size,
                              hipStream_t stream) {
  const float* x    = (const float*)d_in[0];
  const float* cosp = (const float*)d_in[1];
  const float* sinp = (const float*)d_in[2];
  const float* Wq   = (const float*)d_in[3];
  const float* Wk   = (const float*)d_in[4];
  const float* Wv   = (const float*)d_in[5];
  const float* Wo   = (const float*)d_in[6];
  float* out = (float*)d_out;

  char* ws = (char*)d_ws;
  size_t off = 0;
  auto alloc = [&](size_t bytes) {
    void* p = ws + off;
    off += (bytes + 255) & ~(size_t)255;
    return p;
  };
  const size_t MT = (size_t)B_ * T_;  // 4096
  const int NQKV = 3072;              // 2048 q + 512 k + 512 v
  unsigned short* xb    = (unsigned short*)alloc(MT * CEMB * 2);
  unsigned short* wqkvb = (unsigned short*)alloc((size_t)NQKV * 2048 * 2);
  unsigned short* wob   = (unsigned short*)alloc((size_t)2048 * 2048 * 2);
  unsigned short* qkvb  = (unsigned short*)alloc(MT * NQKV * 2);
  unsigned short* qn    = (unsigned short*)alloc((size_t)B_ * H_ * T_ * D_ * 2);
  unsigned short* kn    = (unsigned short*)alloc((size_t)B_ * HKV_ * T_ * D_ * 2);
  unsigned short* vt    = (unsigned short*)alloc((size_t)B_ * HKV_ * D_ * T_ * 2);
  unsigned short* yb    = (unsigned short*)alloc(MT * CEMB * 2);

  // bf16 casts (weights concatenated into [3072][2048])
  cvt_kernel<<<2048, 256, 0, stream>>>(x,  xb, (int)(MT * CEMB / 4));
  cvt_kernel<<<1024, 256, 0, stream>>>(Wq, wqkvb,                2048 * 2048 / 4);
  cvt_kernel<<<256,  256, 0, stream>>>(Wk, wqkvb + 2048 * 2048,  512 * 2048 / 4);
  cvt_kernel<<<256,  256, 0, stream>>>(Wv, wqkvb + 2560 * 2048,  512 * 2048 / 4);
  cvt_kernel<<<1024, 256, 0, stream>>>(Wo, wob,                  2048 * 2048 / 4);

  // fused QKV projection: [4096][3072] bf16
  gemm_bt<<<dim3(NQKV / BN, 4096 / BM), 256, 0, stream>>>(xb, wqkvb, qkvb, 4096, NQKV, 2048, 1);

  // RoPE + RMSNorm; Q gets (1/sqrt(D))*log2(e) folded (softmax in exp2 domain)
  rope_norm<<<4096 * H_,   128, 0, stream>>>(qkvb,        NQKV, cosp, sinp, qn, H_,   0.1275174324f);
  rope_norm<<<4096 * HKV_, 128, 0, stream>>>(qkvb + 2048, NQKV, cosp, sinp, kn, HKV_, 1.0f);
  vtrans<<<dim3(T_ / 64, D_ / 32, B_ * HKV_), 256, 0, stream>>>(qkvb + 2560, NQKV, vt);

  // causal flash attention: pair-balanced blocks (34 tile-iters each)
  attn_kernel<<<dim3(B_ * H_, 8), 256, 0, stream>>>(qn, kn, vt, yb);

  // output projection -> f32 d_out
  gemm_bt<<<dim3(2048 / BN, 4096 / BM), 256, 0, stream>>>(yb, wob, out, 4096, 2048, 2048, 0);
}